// Round 2
// baseline (163.388 us; speedup 1.0000x reference)
//
#include <hip/hip_runtime.h>

// BCH truncated series on 3D periodic velocity fields (fp32, B=2, D=3, 128^3).
// out_i = L_i + R_i + 0.25 * sum_j [ dL_i/dx_j * R_j - dR_i/dx_j * L_j ]
// (central differences with wrap; 0.5 stencil scale * 0.5 BCH folded into 0.25)
//
// Structure (R1): y-marching with rolling registers.
//   thread = (b, x, z-chunk of 4), marches 8 consecutive y values.
//   - y-derivative: rolling window Lm/Lc/Lp — the y+1 line loaded at step t is
//     the center at t+1 and the y-1 line at t+2 (no redundant y-neighbor loads)
//   - z-derivative: in-register shift of the center float4 + 2 lane shuffles
//     (32 lanes cover the full 128-z ring; no z loads at all)
//   - x-derivative: 12 coalesced float4 loads/step (no intra-block reuse exists)
//   All 18 loads per step are independent and issue back-to-back -> high MLP
//   per wave, attacking the latency-bound profile of R0 (HBM 25%, VALU 8%).

namespace {
constexpr int NB = 2, ND = 3, NX = 128, NY = 128, NZ = 128;
constexpr int XS = NY * NZ;          // x stride (floats) = 16384
constexpr int YSEG = 8;              // y values marched per thread
// groups of 32 lanes: NB * NX * (NY/YSEG) = 2*128*16 = 4096
// 8 groups per 256-thread block -> 512 blocks

__device__ inline float4 ld4(const float* p) { return *(const float4*)p; }

__device__ inline float4 f4sub(float4 a, float4 b) {
    return make_float4(a.x - b.x, a.y - b.y, a.z - b.z, a.w - b.w);
}
__device__ inline float4 f4add(float4 a, float4 b) {
    return make_float4(a.x + b.x, a.y + b.y, a.z + b.z, a.w + b.w);
}
// a*b + c
__device__ inline float4 f4fma(float4 a, float4 b, float4 c) {
    return make_float4(fmaf(a.x, b.x, c.x), fmaf(a.y, b.y, c.y),
                       fmaf(a.z, b.z, c.z), fmaf(a.w, b.w, c.w));
}
// c - a*b
__device__ inline float4 f4fms(float4 a, float4 b, float4 c) {
    return make_float4(fmaf(-a.x, b.x, c.x), fmaf(-a.y, b.y, c.y),
                       fmaf(-a.z, b.z, c.z), fmaf(-a.w, b.w, c.w));
}
__device__ inline float4 f4mul(float4 a, float4 b) {
    return make_float4(a.x * b.x, a.y * b.y, a.z * b.z, a.w * b.w);
}

// central z-derivative of a center line held as float4-per-lane over a 32-lane
// z ring: needs lane-1's .w and lane+1's .x
__device__ inline float4 zderiv(float4 c, int srcm, int srcp) {
    const float lw = __shfl(c.w, srcm, 64);
    const float rx = __shfl(c.x, srcp, 64);
    return make_float4(c.y - lw, c.z - c.x, c.w - c.y, rx - c.z);
}
} // namespace

__global__ void __launch_bounds__(256)
bch_kernel(const float* __restrict__ L, const float* __restrict__ R,
           float* __restrict__ O)
{
    const int lane = threadIdx.x & 31;           // z-chunk index within ring
    const int g    = blockIdx.x * 8 + (threadIdx.x >> 5);
    const int yseg = g & 15;
    const int x    = (g >> 4) & 127;
    const int b    = g >> 11;
    const int z0   = lane << 2;
    const int y0   = yseg * YSEG;

    // shuffle sources: ring rotate within each 32-lane half of the wave
    const int wl   = threadIdx.x & 63;
    const int srcm = (wl & 32) | ((wl + 31) & 31);
    const int srcp = (wl & 32) | ((wl + 1) & 31);

    // per-channel base offsets (without the y term)
    int offc[3], offxp[3], offxm[3];
    const int xp = (x + 1) & 127, xm = (x - 1) & 127;
#pragma unroll
    for (int c = 0; c < 3; ++c) {
        const int bc = (b * 3 + c) * NX;
        offc[c]  = (bc + x)  * XS + z0;
        offxp[c] = (bc + xp) * XS + z0;
        offxm[c] = (bc + xm) * XS + z0;
    }

    // prime the rolling window: y0-1 (wrapped) and y0
    float4 Lm[3], Lc[3], Rm[3], Rc[3];
    {
        const int ymo = ((y0 + 127) & 127) * NZ;
        const int yco = y0 * NZ;
#pragma unroll
        for (int c = 0; c < 3; ++c) {
            Lm[c] = ld4(L + offc[c] + ymo);
            Rm[c] = ld4(R + offc[c] + ymo);
            Lc[c] = ld4(L + offc[c] + yco);
            Rc[c] = ld4(R + offc[c] + yco);
        }
    }

    for (int it = 0; it < YSEG; ++it) {
        const int y  = y0 + it;
        const int yr = y * NZ;
        const int yp = ((y + 1) & 127) * NZ;

        // ---- issue all 18 independent loads for this step ----
        float4 Lp[3], Rp[3], LxP[3], LxM[3], RxP[3], RxM[3];
#pragma unroll
        for (int c = 0; c < 3; ++c) {
            Lp[c]  = ld4(L + offc[c]  + yp);
            Rp[c]  = ld4(R + offc[c]  + yp);
            LxP[c] = ld4(L + offxp[c] + yr);
            LxM[c] = ld4(L + offxm[c] + yr);
            RxP[c] = ld4(R + offxp[c] + yr);
            RxM[c] = ld4(R + offxm[c] + yr);
        }

        // z-derivatives of the (already-resident) center lines
        float4 dzL[3], dzR[3];
#pragma unroll
        for (int c = 0; c < 3; ++c) {
            dzL[c] = zderiv(Lc[c], srcm, srcp);
            dzR[c] = zderiv(Rc[c], srcm, srcp);
        }

#pragma unroll
        for (int i = 0; i < 3; ++i) {
            const float4 dxL = f4sub(LxP[i], LxM[i]);
            const float4 dxR = f4sub(RxP[i], RxM[i]);
            const float4 dyL = f4sub(Lp[i], Lm[i]);
            const float4 dyR = f4sub(Rp[i], Rm[i]);

            float4 br = f4fms(dxR, Lc[0], f4mul(dxL, Rc[0]));
            br = f4fms(dyR, Lc[1], f4fma(dyL, Rc[1], br));
            br = f4fms(dzR[i], Lc[2], f4fma(dzL[i], Rc[2], br));

            float4 out = f4add(Lc[i], Rc[i]);
            const float4 q = make_float4(0.25f, 0.25f, 0.25f, 0.25f);
            out = f4fma(q, br, out);
            *(float4*)(O + offc[i] + yr) = out;
        }

        // ---- roll the window ----
#pragma unroll
        for (int c = 0; c < 3; ++c) {
            Lm[c] = Lc[c]; Lc[c] = Lp[c];
            Rm[c] = Rc[c]; Rc[c] = Rp[c];
        }
    }
}

extern "C" void kernel_launch(void* const* d_in, const int* in_sizes, int n_in,
                              void* d_out, int out_size, void* d_ws, size_t ws_size,
                              hipStream_t stream)
{
    const float* L = (const float*)d_in[0];
    const float* R = (const float*)d_in[1];
    float*       O = (float*)d_out;

    // 4096 lane-groups of 32, 8 per block
    dim3 grid(512), block(256);
    bch_kernel<<<grid, block, 0, stream>>>(L, R, O);
}

// Round 4
// 153.517 us; speedup vs baseline: 1.0643x; 1.0643x over previous
//
#include <hip/hip_runtime.h>

// BCH truncated series on 3D periodic velocity fields (fp32, B=2, D=3, 128^3).
// out_i = L_i + R_i + 0.25 * sum_j [ dL_i/dx_j * R_j - dR_i/dx_j * L_j ]
//
// R4 structure: R0's high-occupancy mapping (1M threads; thread = (b,x,y,
// 4-wide z chunk), all 3 channels per thread) with ALL loads hoisted into one
// dependency-free batch (30 float4 + 12 scalar z-halo loads -> one s_waitcnt
// round instead of R0's ~9 serialized rounds; attacks the latency-bound
// profile: R0 showed HBM 25%, VALU 8%, occupancy 44%).
// z-derivative = in-register shift of the center float4 + 2 wrapped scalars
// (exactly R0's validated scheme — R3's cross-lane shuffle variant failed the
// post-timing check, so shuffles are removed to shrink the novel surface).
// R1 lesson: keep TLP — 4096 blocks, not 512.

namespace {
constexpr int NX = 128, NY = 128, NZ = 128;
constexpr int XS = NY * NZ;   // x stride = 16384 floats
constexpr int CS = NX * XS;   // channel stride

__device__ inline float4 ld4(const float* p) { return *(const float4*)p; }

__device__ inline float4 f4sub(float4 a, float4 b) {
    return make_float4(a.x - b.x, a.y - b.y, a.z - b.z, a.w - b.w);
}
__device__ inline float4 f4add(float4 a, float4 b) {
    return make_float4(a.x + b.x, a.y + b.y, a.z + b.z, a.w + b.w);
}
__device__ inline float4 f4mul(float4 a, float4 b) {
    return make_float4(a.x * b.x, a.y * b.y, a.z * b.z, a.w * b.w);
}
// a*b + c
__device__ inline float4 f4fma(float4 a, float4 b, float4 c) {
    return make_float4(fmaf(a.x, b.x, c.x), fmaf(a.y, b.y, c.y),
                       fmaf(a.z, b.z, c.z), fmaf(a.w, b.w, c.w));
}
// c - a*b
__device__ inline float4 f4fms(float4 a, float4 b, float4 c) {
    return make_float4(fmaf(-a.x, b.x, c.x), fmaf(-a.y, b.y, c.y),
                       fmaf(-a.z, b.z, c.z), fmaf(-a.w, b.w, c.w));
}
} // namespace

__global__ void __launch_bounds__(256)
bch_kernel(const float* __restrict__ L, const float* __restrict__ R,
           float* __restrict__ O)
{
    const int tid = blockIdx.x * 256 + threadIdx.x;   // 20 bits
    const int zc  = tid & 31;                         // z-chunk index
    const int y   = (tid >> 5) & 127;
    const int x   = (tid >> 12) & 127;
    const int b   = tid >> 19;
    const int z0  = zc << 2;

    const int xp = (x + 1) & 127, xm = (x - 1) & 127;
    const int yp = (y + 1) & 127, ym = (y - 1) & 127;
    const int ozm = ((z0 - 1) & 127) - z0;   // rel offset to wrapped z0-1
    const int ozp = ((z0 + 4) & 127) - z0;   // rel offset to wrapped z0+4

    // ---- one dependency-free batch: 30 float4 + 12 scalar loads ----
    float4 lC[3], rC[3], lXP[3], lXM[3], rXP[3], rXM[3],
           lYP[3], lYM[3], rYP[3], rYM[3];
    float  lzm[3], lzp[3], rzm[3], rzp[3];
    int    occ[3];
#pragma unroll
    for (int c = 0; c < 3; ++c) {
        const int bc  = (b * 3 + c) * NX;
        const int oc  = (bc + x)  * XS + y  * NZ + z0;
        const int oxp = (bc + xp) * XS + y  * NZ + z0;
        const int oxm = (bc + xm) * XS + y  * NZ + z0;
        const int oyp = (bc + x)  * XS + yp * NZ + z0;
        const int oym = (bc + x)  * XS + ym * NZ + z0;
        occ[c] = oc;
        lC[c]  = ld4(L + oc);   rC[c]  = ld4(R + oc);
        lXP[c] = ld4(L + oxp);  rXP[c] = ld4(R + oxp);
        lXM[c] = ld4(L + oxm);  rXM[c] = ld4(R + oxm);
        lYP[c] = ld4(L + oyp);  rYP[c] = ld4(R + oyp);
        lYM[c] = ld4(L + oym);  rYM[c] = ld4(R + oym);
        lzm[c] = L[oc + ozm];   lzp[c] = L[oc + ozp];
        rzm[c] = R[oc + ozm];   rzp[c] = R[oc + ozp];
    }

#pragma unroll
    for (int i = 0; i < 3; ++i) {
        const float4 dxL = f4sub(lXP[i], lXM[i]);
        const float4 dxR = f4sub(rXP[i], rXM[i]);
        const float4 dyL = f4sub(lYP[i], lYM[i]);
        const float4 dyR = f4sub(rYP[i], rYM[i]);
        // z-derivative: shift-in-register from center + wrapped scalar halos
        const float4 dzL = make_float4(lC[i].y - lzm[i], lC[i].z - lC[i].x,
                                       lC[i].w - lC[i].y, lzp[i] - lC[i].z);
        const float4 dzR = make_float4(rC[i].y - rzm[i], rC[i].z - rC[i].x,
                                       rC[i].w - rC[i].y, rzp[i] - rC[i].z);

        float4 br = f4fms(dxR, lC[0], f4mul(dxL, rC[0]));
        br = f4fms(dyR, lC[1], f4fma(dyL, rC[1], br));
        br = f4fms(dzR, lC[2], f4fma(dzL, rC[2], br));

        float4 out = f4add(lC[i], rC[i]);
        const float4 q = make_float4(0.25f, 0.25f, 0.25f, 0.25f);
        out = f4fma(q, br, out);
        *(float4*)(O + occ[i]) = out;
    }
}

extern "C" void kernel_launch(void* const* d_in, const int* in_sizes, int n_in,
                              void* d_out, int out_size, void* d_ws, size_t ws_size,
                              hipStream_t stream)
{
    const float* L = (const float*)d_in[0];
    const float* R = (const float*)d_in[1];
    float*       O = (float*)d_out;

    dim3 grid(4096), block(256);   // 2*128*128*32 threads / 256
    bch_kernel<<<grid, block, 0, stream>>>(L, R, O);
}